// Round 10
// baseline (540.240 us; speedup 1.0000x reference)
//
#include <hip/hip_runtime.h>
#include <math.h>

#define BG   128            // graphs
#define NPER 1024           // nodes per graph, level 0
#define HDIM 128            // hidden
#define NEDGE (BG * NPER * 8)
#define NMAX (BG * NPER)    // 131072
#define CAP  48             // per-node edge capacity (Poisson(8) tail ~1e-15)
#define PRE  16             // packed-meta entries per node (P(deg>16) ~ 0.4%)
#define CH   32             // channels per agg chunk
#define CHUNKS 4            // 128 / CH

// ---------------------------------------------------------------------------
// p-norms for the three pooling vectors
// ---------------------------------------------------------------------------

__global__ __launch_bounds__(128) void pnorm_kernel(
    const float* __restrict__ p1, const float* __restrict__ p2,
    const float* __restrict__ p3, float* __restrict__ pn) {
  const float* p = blockIdx.x == 0 ? p1 : (blockIdx.x == 1 ? p2 : p3);
  __shared__ float red[128];
  int t = threadIdx.x;
  float v = p[t];
  red[t] = v * v;
  __syncthreads();
  for (int off = 64; off; off >>= 1) {
    if (t < off) red[t] += red[t + off];
    __syncthreads();
  }
  if (t == 0) pn[blockIdx.x] = sqrtf(red[0]);
}

// ---------------------------------------------------------------------------
// L0 in-degree count straight from the input edge list (cnt pre-zeroed)
// ---------------------------------------------------------------------------

__global__ __launch_bounds__(256) void count_kernel(
    const int* __restrict__ ec, int* __restrict__ cnt) {
  int e = blockIdx.x * 256 + threadIdx.x;
  atomicAdd(&cnt[ec[e]], 1);
}

// ---------------------------------------------------------------------------
// prep: dinv from counts; zero fill-cursor; init newid = -1
// ---------------------------------------------------------------------------

__global__ __launch_bounds__(256) void prep_kernel(
    const int* __restrict__ cnt, float* __restrict__ dinv,
    int* __restrict__ cursor, int* __restrict__ newid) {
  int i = blockIdx.x * 256 + threadIdx.x;
  dinv[i] = rsqrtf((float)cnt[i] + 1.0f);
  cursor[i] = 0;
  newid[i] = -1;
}

// ---------------------------------------------------------------------------
// fill: packed per-node meta (graph-LOCAL src, coef) for the first PRE edges;
// overflow (rare) to srcext/cfext. mask = nodes-per-graph - 1.
// ---------------------------------------------------------------------------

__global__ __launch_bounds__(256) void fill_kernel(
    const int* __restrict__ cr, const int* __restrict__ cc,
    const float* __restrict__ dinv, int* __restrict__ cursor,
    int2* __restrict__ meta16, int* __restrict__ srcext,
    float* __restrict__ cfext, int mask) {
  int e = blockIdx.x * 256 + threadIdx.x;
  int c = cc[e];
  if (c >= 0) {
    int r = cr[e];
    int pos = atomicAdd(&cursor[c], 1);
    float cf = dinv[r] * dinv[c];
    int rl = r & mask;                  // graph-local row index
    if (pos < PRE) {
      meta16[(size_t)c * PRE + pos] = make_int2(rl, __float_as_int(cf));
    } else if (pos < CAP) {
      srcext[(size_t)c * CAP + pos] = rl;
      cfext[(size_t)c * CAP + pos] = cf;
    }
  }
}

// ---------------------------------------------------------------------------
// LDS-resident aggregation: block = (graph, 32-channel chunk).
//  stage x[graph][:, chunk] (npg x 128 B) + dinv -> LDS (coalesced, read ONCE)
//  per 128-dst pass: stage packed meta (16 KB) -> 8 lanes/dst gather rows from
//  LDS via ds_read_b128 and FMA. dynamic LDS: npg*33*4 + 16384 B (L0: 148 KB).
// ---------------------------------------------------------------------------

extern __shared__ float ldsbuf[];

__global__ __launch_bounds__(1024) void agg_lds_kernel(
    const float* __restrict__ x, float* __restrict__ z,
    const int2* __restrict__ meta16, const int* __restrict__ srcext,
    const float* __restrict__ cfext, const int* __restrict__ deg,
    const float* __restrict__ dinv, int npg) {
  float* sX = ldsbuf;                          // [npg][32]
  float* sDinv = sX + npg * 32;                // [npg]
  int2* sMeta = (int2*)(sDinv + npg);          // [128][PRE]
  int g = blockIdx.x >> 2;
  int chunk = blockIdx.x & 3;
  int t = threadIdx.x;
  int base = g * npg;

  const float4* x4 = (const float4*)x;
  float4* sX4 = (float4*)sX;
  for (int i = t; i < npg * 8; i += 1024) {
    int r = i >> 3, l8 = i & 7;
    sX4[i] = x4[(size_t)(base + r) * 32 + chunk * 8 + l8];
  }
  for (int i = t; i < npg; i += 1024) sDinv[i] = dinv[base + i];
  __syncthreads();

  int passes = npg >> 7;
  int dl = t >> 3, l = t & 7;                  // dst-local 0..127, lane 0..7
  for (int pass = 0; pass < passes; ++pass) {
    {
      const int4* gm = (const int4*)(meta16 + (size_t)(base + pass * 128) * PRE);
      ((int4*)sMeta)[t] = gm[t];
    }
    __syncthreads();
    int dst = pass * 128 + dl;
    int node = base + dst;
    int d = deg[node];
    if (d > CAP) d = CAP;
    float dc = sDinv[dst];
    float s0 = dc * dc;
    float4 row = sX4[dst * 8 + l];
    float4 a0 = make_float4(row.x * s0, row.y * s0, row.z * s0, row.w * s0);
    float4 a1 = make_float4(0.f, 0.f, 0.f, 0.f);
    int dp = d < PRE ? d : PRE;
    const int2* m = &sMeta[dl * PRE];
    const int4* m4 = (const int4*)m;
    int e = 0;
    for (; e + 1 < dp; e += 2) {               // 2 edges per b128 meta read
      int4 q = m4[e >> 1];
      float4 v0 = sX4[q.x * 8 + l];
      float4 v1 = sX4[q.z * 8 + l];
      float c0 = __int_as_float(q.y), c1 = __int_as_float(q.w);
      a0.x = fmaf(v0.x, c0, a0.x); a0.y = fmaf(v0.y, c0, a0.y);
      a0.z = fmaf(v0.z, c0, a0.z); a0.w = fmaf(v0.w, c0, a0.w);
      a1.x = fmaf(v1.x, c1, a1.x); a1.y = fmaf(v1.y, c1, a1.y);
      a1.z = fmaf(v1.z, c1, a1.z); a1.w = fmaf(v1.w, c1, a1.w);
    }
    if (e < dp) {
      int2 pr = m[e];
      float4 v0 = sX4[pr.x * 8 + l];
      float c0 = __int_as_float(pr.y);
      a0.x = fmaf(v0.x, c0, a0.x); a0.y = fmaf(v0.y, c0, a0.y);
      a0.z = fmaf(v0.z, c0, a0.z); a0.w = fmaf(v0.w, c0, a0.w);
    }
    for (int e2 = PRE; e2 < d; ++e2) {         // rare overflow (deg > 16)
      int rl = srcext[(size_t)node * CAP + e2];
      float cf = cfext[(size_t)node * CAP + e2];
      float4 v0 = sX4[rl * 8 + l];
      a0.x = fmaf(v0.x, cf, a0.x); a0.y = fmaf(v0.y, cf, a0.y);
      a0.z = fmaf(v0.z, cf, a0.z); a0.w = fmaf(v0.w, cf, a0.w);
    }
    float4 o = make_float4(a0.x + a1.x, a0.y + a1.y, a0.z + a1.z, a0.w + a1.w);
    ((float4*)z)[(size_t)node * 32 + chunk * 8 + l] = o;
    __syncthreads();                           // before next pass's meta stage
  }
}

// ---------------------------------------------------------------------------
// conv: h = relu(z @ W + b), in-place on zh; also score[row] = h . p
// tile: 64 rows x 128 cols, block 256 (8 rows x 4 cols per thread).
// W streams from L1/L2 (round-9 showed LDS-staging W regresses: LDS pipe is
// the scarce resource, W is L1-broadcast-friendly). 1-stage software pipeline
// on W: next k4's 4 loads issue before current k4's 128 FMAs (guideline 7).
// ---------------------------------------------------------------------------

__global__ __launch_bounds__(256) void conv_kernel(
    float* __restrict__ zh, const float* __restrict__ W,
    const float* __restrict__ bias, const float* __restrict__ p,
    float* __restrict__ score) {
  __shared__ float sZ[64 * HDIM];              // 32 KB
  int tid = threadIdx.x;
  size_t base = (size_t)blockIdx.x * 64 * HDIM;
  float4* sZ4 = (float4*)sZ;
  const float4* g4 = (const float4*)(zh + base);
  #pragma unroll
  for (int i = 0; i < 8; ++i) sZ4[i * 256 + tid] = g4[i * 256 + tid];
  __syncthreads();

  int col_t = tid & 31;
  int row_t = tid >> 5;
  int r0 = row_t * 8;
  const float4* W4 = (const float4*)W;

  float acc[8][4];
  #pragma unroll
  for (int r = 0; r < 8; ++r)
    #pragma unroll
    for (int c = 0; c < 4; ++c) acc[r][c] = 0.f;

  float4 w0 = W4[0 * 32 + col_t];
  float4 w1 = W4[1 * 32 + col_t];
  float4 w2 = W4[2 * 32 + col_t];
  float4 w3 = W4[3 * 32 + col_t];

  for (int k4 = 0; k4 < 32; ++k4) {
    int kn = k4 + 1;
    if (kn > 31) kn = 31;                      // branchless: redundant last load
    float4 nw0 = W4[(kn * 4 + 0) * 32 + col_t];
    float4 nw1 = W4[(kn * 4 + 1) * 32 + col_t];
    float4 nw2 = W4[(kn * 4 + 2) * 32 + col_t];
    float4 nw3 = W4[(kn * 4 + 3) * 32 + col_t];
    #pragma unroll
    for (int r = 0; r < 8; ++r) {
      float4 zr = sZ4[(r0 + r) * 32 + k4];
      acc[r][0] = fmaf(zr.x, w0.x, acc[r][0]);
      acc[r][1] = fmaf(zr.x, w0.y, acc[r][1]);
      acc[r][2] = fmaf(zr.x, w0.z, acc[r][2]);
      acc[r][3] = fmaf(zr.x, w0.w, acc[r][3]);
      acc[r][0] = fmaf(zr.y, w1.x, acc[r][0]);
      acc[r][1] = fmaf(zr.y, w1.y, acc[r][1]);
      acc[r][2] = fmaf(zr.y, w1.z, acc[r][2]);
      acc[r][3] = fmaf(zr.y, w1.w, acc[r][3]);
      acc[r][0] = fmaf(zr.z, w2.x, acc[r][0]);
      acc[r][1] = fmaf(zr.z, w2.y, acc[r][1]);
      acc[r][2] = fmaf(zr.z, w2.z, acc[r][2]);
      acc[r][3] = fmaf(zr.z, w2.w, acc[r][3]);
      acc[r][0] = fmaf(zr.w, w3.x, acc[r][0]);
      acc[r][1] = fmaf(zr.w, w3.y, acc[r][1]);
      acc[r][2] = fmaf(zr.w, w3.z, acc[r][2]);
      acc[r][3] = fmaf(zr.w, w3.w, acc[r][3]);
    }
    w0 = nw0; w1 = nw1; w2 = nw2; w3 = nw3;
  }

  float4 bv = ((const float4*)bias)[col_t];
  float4 pv = ((const float4*)p)[col_t];
  float4* out4 = (float4*)(zh + base);
  #pragma unroll
  for (int r = 0; r < 8; ++r) {
    float hx = fmaxf(acc[r][0] + bv.x, 0.f);
    float hy = fmaxf(acc[r][1] + bv.y, 0.f);
    float hz = fmaxf(acc[r][2] + bv.z, 0.f);
    float hw = fmaxf(acc[r][3] + bv.w, 0.f);
    float part = hx * pv.x + hy * pv.y + hz * pv.z + hw * pv.w;
    #pragma unroll
    for (int sft = 1; sft < 32; sft <<= 1) part += __shfl_xor(part, sft);
    out4[(r0 + r) * 32 + col_t] = make_float4(hx, hy, hz, hw);
    if (col_t == 0) score[blockIdx.x * 64 + r0 + r] = part;
  }
}

// ---------------------------------------------------------------------------
// per-graph top-K (K = P/2): P-thread bitonic sort, one element per thread.
// descending, tie-break lower index. Also zeroes cnt for next layer.
// ---------------------------------------------------------------------------

__global__ __launch_bounds__(1024) void topk_kernel(
    const float* __restrict__ score, const float* __restrict__ pnorm,
    int* __restrict__ sel, float* __restrict__ tanhv, int* __restrict__ newid,
    int* __restrict__ cnt_next, int P, int K) {
  __shared__ float sv[1024];
  __shared__ int si[1024];
  int g = blockIdx.x;
  int t = threadIdx.x;
  if (t < K) cnt_next[g * K + t] = 0;
  sv[t] = score[(size_t)g * P + t];
  si[t] = t;
  for (int size = 2; size <= P; size <<= 1) {
    for (int stride = size >> 1; stride; stride >>= 1) {
      __syncthreads();
      int j = t ^ stride;
      if (j > t) {
        float a = sv[t], b = sv[j];
        int ia = si[t], ib = si[j];
        bool tFirst = (a > b) || (a == b && ia < ib);
        bool up = ((t & size) == 0);
        if (up ? !tFirst : tFirst) {
          sv[t] = b; sv[j] = a;
          si[t] = ib; si[j] = ia;
        }
      }
    }
  }
  __syncthreads();
  if (t < K) {
    float v = sv[t];
    int oldg = g * P + si[t];
    int newg = g * K + t;
    sel[newg] = oldg;
    tanhv[newg] = tanhf(v / pnorm[0]);
    newid[oldg] = newg;
  }
}

// ---------------------------------------------------------------------------
// pool gather: xo[j] = h[sel[j]] * tanhv[j] for a 16-row chunk; float4 lanes.
// ---------------------------------------------------------------------------

__global__ __launch_bounds__(256) void pool_gather_kernel(
    const float* __restrict__ h, const int* __restrict__ sel,
    const float* __restrict__ tanhv, float* __restrict__ xo,
    float* __restrict__ pred, int K, int lc) {
  __shared__ int s_sel[16];
  __shared__ float s_th[16];
  __shared__ float4 smx[8][32], ssm[8][32];
  int b = blockIdx.x;
  int g = b >> lc;
  int chunk = b & ((1 << lc) - 1);
  int t = threadIdx.x;
  int j0 = chunk * 16;
  if (t < 16) {
    s_sel[t] = sel[g * K + j0 + t];
    s_th[t] = tanhv[g * K + j0 + t];
  }
  __syncthreads();
  int lane = t & 31, slot = t >> 5;
  const float4* h4 = (const float4*)h;
  float4* xo4 = (float4*)xo;
  float4 mx = make_float4(-INFINITY, -INFINITY, -INFINITY, -INFINITY);
  float4 sm = make_float4(0.f, 0.f, 0.f, 0.f);
  #pragma unroll
  for (int i = 0; i < 2; ++i) {
    int j = slot + i * 8;
    float th = s_th[j];
    float4 v = h4[(size_t)s_sel[j] * 32 + lane];
    v.x *= th; v.y *= th; v.z *= th; v.w *= th;
    xo4[(size_t)(g * K + j0 + j) * 32 + lane] = v;
    mx.x = fmaxf(mx.x, v.x); mx.y = fmaxf(mx.y, v.y);
    mx.z = fmaxf(mx.z, v.z); mx.w = fmaxf(mx.w, v.w);
    sm.x += v.x; sm.y += v.y; sm.z += v.z; sm.w += v.w;
  }
  smx[slot][lane] = mx;
  ssm[slot][lane] = sm;
  __syncthreads();
  if (slot == 0) {
    #pragma unroll
    for (int s2 = 1; s2 < 8; ++s2) {
      float4 m2 = smx[s2][lane], s3 = ssm[s2][lane];
      mx.x = fmaxf(mx.x, m2.x); mx.y = fmaxf(mx.y, m2.y);
      mx.z = fmaxf(mx.z, m2.z); mx.w = fmaxf(mx.w, m2.w);
      sm.x += s3.x; sm.y += s3.y; sm.z += s3.z; sm.w += s3.w;
    }
    float4* pred4 = (float4*)pred;
    pred4[(size_t)(g * 32 + chunk) * 64 + lane] = mx;
    pred4[(size_t)(g * 32 + chunk) * 64 + 32 + lane] = sm;
  }
}

// ---------------------------------------------------------------------------
// pool combine: reduce C chunk-partials per graph, accumulate into out
// ---------------------------------------------------------------------------

__global__ __launch_bounds__(64) void pool_combine_kernel(
    const float* __restrict__ pred, float* __restrict__ out, int K, int C) {
  int g = blockIdx.x;
  int t = threadIdx.x;
  const float4* pred4 = (const float4*)pred;
  float4* out4 = (float4*)out;
  if (t < 32) {
    float4 mx = make_float4(-INFINITY, -INFINITY, -INFINITY, -INFINITY);
    for (int c = 0; c < C; ++c) {
      float4 v = pred4[(size_t)(g * 32 + c) * 64 + t];
      mx.x = fmaxf(mx.x, v.x); mx.y = fmaxf(mx.y, v.y);
      mx.z = fmaxf(mx.z, v.z); mx.w = fmaxf(mx.w, v.w);
    }
    float4 o = out4[g * 64 + t];
    o.x += mx.x; o.y += mx.y; o.z += mx.z; o.w += mx.w;
    out4[g * 64 + t] = o;
  } else {
    int l = t - 32;
    float4 sm = make_float4(0.f, 0.f, 0.f, 0.f);
    for (int c = 0; c < C; ++c) {
      float4 v = pred4[(size_t)(g * 32 + c) * 64 + 32 + l];
      sm.x += v.x; sm.y += v.y; sm.z += v.z; sm.w += v.w;
    }
    float inv = 1.0f / (float)K;
    float4 o = out4[g * 64 + 32 + l];
    o.x += sm.x * inv; o.y += sm.y * inv; o.z += sm.z * inv; o.w += sm.w * inv;
    out4[g * 64 + 32 + l] = o;
  }
}

// ---------------------------------------------------------------------------
// fused relabel + count for next layer (cnt zeroed by topk)
// ---------------------------------------------------------------------------

__global__ __launch_bounds__(256) void relabel_count_kernel(
    const int* __restrict__ in_r, const int* __restrict__ in_c,
    int* __restrict__ out_r, int* __restrict__ out_c,
    const int* __restrict__ newid, int* __restrict__ cnt) {
  int e = blockIdx.x * 256 + threadIdx.x;
  int r = in_r[e];
  if (r < 0) {
    out_r[e] = -1;
    out_c[e] = -1;
    return;
  }
  int nr = newid[r];
  int nc = newid[in_c[e]];
  if (nr < 0 || nc < 0) {
    out_r[e] = -1;
    out_c[e] = -1;
  } else {
    out_r[e] = nr;
    out_c[e] = nc;
    atomicAdd(&cnt[nc], 1);
  }
}

// ---------------------------------------------------------------------------
// launch
// ---------------------------------------------------------------------------

extern "C" void kernel_launch(void* const* d_in, const int* in_sizes, int n_in,
                              void* d_out, int out_size, void* d_ws, size_t ws_size,
                              hipStream_t stream) {
  const float* x0 = (const float*)d_in[0];
  const int* erow = (const int*)d_in[1];
  const int* ecol = (const int*)d_in[2];
  const float* Wm[3] = {(const float*)d_in[3], (const float*)d_in[6], (const float*)d_in[9]};
  const float* bm[3] = {(const float*)d_in[4], (const float*)d_in[7], (const float*)d_in[10]};
  const float* pm[3] = {(const float*)d_in[5], (const float*)d_in[8], (const float*)d_in[11]};

  char* w = (char*)d_ws;
  size_t off = 0;
  auto alloc = [&](size_t bytes) -> void* {
    void* ptr = w + off;
    off = (off + bytes + 255) & ~(size_t)255;
    return ptr;
  };
  int* cur_row = (int*)alloc((size_t)NEDGE * 4);
  int* cur_col = (int*)alloc((size_t)NEDGE * 4);
  int2* meta16 = (int2*)alloc((size_t)NMAX * PRE * 8);
  int* srcext  = (int*)alloc((size_t)NMAX * CAP * 4);
  float* cfext = (float*)alloc((size_t)NMAX * CAP * 4);
  int* cnt     = (int*)alloc((size_t)NMAX * 4);
  int* cursor  = (int*)alloc((size_t)NMAX * 4);
  float* dinv  = (float*)alloc((size_t)NMAX * 4);
  int* newid   = (int*)alloc((size_t)NMAX * 4);
  float* score = (float*)alloc((size_t)NMAX * 4);
  int* sel     = (int*)alloc((size_t)BG * 512 * 4);
  float* tanhv = (float*)alloc((size_t)BG * 512 * 4);
  float* pn    = (float*)alloc(256);
  float* pred  = (float*)alloc((size_t)BG * 32 * 256 * 4);
  float* zh    = (float*)alloc((size_t)NMAX * HDIM * 4);
  float* x1    = (float*)alloc((size_t)BG * 512 * HDIM * 4);
  float* x2    = (float*)alloc((size_t)BG * 256 * HDIM * 4);
  float* x3    = (float*)alloc((size_t)BG * 128 * HDIM * 4);

  // allow >64 KB dynamic LDS for the agg kernel (L0 needs 148 KB)
  hipFuncSetAttribute((const void*)agg_lds_kernel,
                      hipFuncAttributeMaxDynamicSharedMemorySize, 152 * 1024);

  hipMemsetAsync(d_out, 0, (size_t)out_size * 4, stream);
  hipMemsetAsync(cnt, 0, (size_t)NMAX * 4, stream);
  pnorm_kernel<<<3, 128, 0, stream>>>(pm[0], pm[1], pm[2], pn);
  count_kernel<<<NEDGE / 256, 256, 0, stream>>>(ecol, cnt);

  const float* xin = x0;
  float* xout[3] = {x1, x2, x3};
  int Ps[3] = {1024, 512, 256};
  int LCs[3] = {5, 4, 3};     // log2(K/16)

  for (int L = 0; L < 3; ++L) {
    int P = Ps[L];
    int K = P >> 1;
    int n = BG * P;
    int lc = LCs[L];
    int C = 1 << lc;
    const int* in_r = (L == 0) ? erow : cur_row;
    const int* in_c = (L == 0) ? ecol : cur_col;
    size_t ldsBytes = (size_t)(P * 32 + P) * 4 + 16384;

    prep_kernel<<<n / 256, 256, 0, stream>>>(cnt, dinv, cursor, newid);
    fill_kernel<<<NEDGE / 256, 256, 0, stream>>>(in_r, in_c, dinv, cursor,
                                                 meta16, srcext, cfext, P - 1);
    agg_lds_kernel<<<BG * CHUNKS, 1024, ldsBytes, stream>>>(
        xin, zh, meta16, srcext, cfext, cursor, dinv, P);
    conv_kernel<<<n / 64, 256, 0, stream>>>(zh, Wm[L], bm[L], pm[L], score);
    topk_kernel<<<BG, P, 0, stream>>>(score, pn + L, sel, tanhv, newid, cnt, P, K);
    pool_gather_kernel<<<BG * C, 256, 0, stream>>>(zh, sel, tanhv, xout[L], pred, K, lc);
    pool_combine_kernel<<<BG, 64, 0, stream>>>(pred, (float*)d_out, K, C);
    if (L < 2) relabel_count_kernel<<<NEDGE / 256, 256, 0, stream>>>(
        in_r, in_c, cur_row, cur_col, newid, cnt);
    xin = xout[L];
  }
}

// Round 11
// 527.122 us; speedup vs baseline: 1.0249x; 1.0249x over previous
//
#include <hip/hip_runtime.h>
#include <math.h>

#define BG   128            // graphs
#define NPER 1024           // nodes per graph, level 0
#define HDIM 128            // hidden
#define NEDGE (BG * NPER * 8)
#define NMAX (BG * NPER)    // 131072
#define CAP  48             // per-node edge capacity (Poisson(8) tail ~1e-15)
#define PRE  16             // packed-meta entries per node (P(deg>16) ~ 0.4%)
#define CHUNKS 4            // 128 / 32 channels per agg chunk

typedef float v2f __attribute__((ext_vector_type(2)));

static __device__ __forceinline__ v2f pkfma(v2f a, v2f b, v2f c) {
#if __has_builtin(__builtin_elementwise_fma)
  return __builtin_elementwise_fma(a, b, c);
#else
  v2f r; r.x = fmaf(a.x, b.x, c.x); r.y = fmaf(a.y, b.y, c.y); return r;
#endif
}

// ---------------------------------------------------------------------------
// p-norms for the three pooling vectors
// ---------------------------------------------------------------------------

__global__ __launch_bounds__(128) void pnorm_kernel(
    const float* __restrict__ p1, const float* __restrict__ p2,
    const float* __restrict__ p3, float* __restrict__ pn) {
  const float* p = blockIdx.x == 0 ? p1 : (blockIdx.x == 1 ? p2 : p3);
  __shared__ float red[128];
  int t = threadIdx.x;
  float v = p[t];
  red[t] = v * v;
  __syncthreads();
  for (int off = 64; off; off >>= 1) {
    if (t < off) red[t] += red[t + off];
    __syncthreads();
  }
  if (t == 0) pn[blockIdx.x] = sqrtf(red[0]);
}

// ---------------------------------------------------------------------------
// L0 in-degree count straight from the input edge list (cnt pre-zeroed)
// ---------------------------------------------------------------------------

__global__ __launch_bounds__(256) void count_kernel(
    const int* __restrict__ ec, int* __restrict__ cnt) {
  int e = blockIdx.x * 256 + threadIdx.x;
  atomicAdd(&cnt[ec[e]], 1);
}

// ---------------------------------------------------------------------------
// prep: dinv from counts; zero fill-cursor; init newid = -1
// ---------------------------------------------------------------------------

__global__ __launch_bounds__(256) void prep_kernel(
    const int* __restrict__ cnt, float* __restrict__ dinv,
    int* __restrict__ cursor, int* __restrict__ newid) {
  int i = blockIdx.x * 256 + threadIdx.x;
  dinv[i] = rsqrtf((float)cnt[i] + 1.0f);
  cursor[i] = 0;
  newid[i] = -1;
}

// ---------------------------------------------------------------------------
// fill: packed per-node meta (graph-LOCAL src, coef) for the first PRE edges;
// overflow (rare) to srcext/cfext. mask = nodes-per-graph - 1.
// ---------------------------------------------------------------------------

__global__ __launch_bounds__(256) void fill_kernel(
    const int* __restrict__ cr, const int* __restrict__ cc,
    const float* __restrict__ dinv, int* __restrict__ cursor,
    int2* __restrict__ meta16, int* __restrict__ srcext,
    float* __restrict__ cfext, int mask) {
  int e = blockIdx.x * 256 + threadIdx.x;
  int c = cc[e];
  if (c >= 0) {
    int r = cr[e];
    int pos = atomicAdd(&cursor[c], 1);
    float cf = dinv[r] * dinv[c];
    int rl = r & mask;                  // graph-local row index
    if (pos < PRE) {
      meta16[(size_t)c * PRE + pos] = make_int2(rl, __float_as_int(cf));
    } else if (pos < CAP) {
      srcext[(size_t)c * CAP + pos] = rl;
      cfext[(size_t)c * CAP + pos] = cf;
    }
  }
}

// ---------------------------------------------------------------------------
// LDS-resident aggregation, barrier-free gather phase:
//  block = (graph, 32-channel chunk); stage x slice + dinv -> LDS (read ONCE),
//  ONE barrier, then each 8-lane group walks its dsts independently:
//  meta = one coalesced int4/lane (2 edges), broadcast via __shfl; rows
//  gathered from LDS ds_read_b128. No per-pass barriers (round-10 showed
//  the 8 per-pass barriers on a 16-wave 1-block/CU kernel were the stall).
//  dynamic LDS: npg*33*4 B (L0: 132 KB).
// ---------------------------------------------------------------------------

extern __shared__ float ldsbuf[];

__global__ __launch_bounds__(1024) void agg_lds_kernel(
    const float* __restrict__ x, float* __restrict__ z,
    const int2* __restrict__ meta16, const int* __restrict__ srcext,
    const float* __restrict__ cfext, const int* __restrict__ deg,
    const float* __restrict__ dinv, int npg) {
  float* sX = ldsbuf;                          // [npg][32]
  float* sDinv = sX + npg * 32;                // [npg]
  int g = blockIdx.x >> 2;
  int chunk = blockIdx.x & 3;
  int t = threadIdx.x;
  int base = g * npg;

  const float4* x4 = (const float4*)x;
  float4* sX4 = (float4*)sX;
  for (int i = t; i < npg * 8; i += 1024) {
    int r = i >> 3, l8 = i & 7;
    sX4[i] = x4[(size_t)(base + r) * 32 + chunk * 8 + l8];
  }
  for (int i = t; i < npg; i += 1024) sDinv[i] = dinv[base + i];
  __syncthreads();

  int dl = t >> 3, l = t & 7;                  // dst-local slot, lane 0..7
  int base8 = (t & 63) & 56;                   // 8-lane group base within wave
  const int4* m4 = (const int4*)meta16;
  for (int dst = dl; dst < npg; dst += 128) {
    int node = base + dst;
    int4 mq = m4[(size_t)node * 8 + l];        // edges 2l, 2l+1 (coalesced)
    int d = deg[node];
    if (d > CAP) d = CAP;
    float dc = sDinv[dst];
    float s0 = dc * dc;
    float4 row = sX4[dst * 8 + l];
    float4 a0 = make_float4(row.x * s0, row.y * s0, row.z * s0, row.w * s0);
    float4 a1 = make_float4(0.f, 0.f, 0.f, 0.f);
    int dp = d < PRE ? d : PRE;
    int e = 0;
    for (; e + 1 < dp; e += 2) {
      int sl = base8 + (e >> 1);
      int si0 = __shfl(mq.x, sl);
      int si1 = __shfl(mq.z, sl);
      float c0 = __int_as_float(__shfl(mq.y, sl));
      float c1 = __int_as_float(__shfl(mq.w, sl));
      float4 v0 = sX4[si0 * 8 + l];
      float4 v1 = sX4[si1 * 8 + l];
      a0.x = fmaf(v0.x, c0, a0.x); a0.y = fmaf(v0.y, c0, a0.y);
      a0.z = fmaf(v0.z, c0, a0.z); a0.w = fmaf(v0.w, c0, a0.w);
      a1.x = fmaf(v1.x, c1, a1.x); a1.y = fmaf(v1.y, c1, a1.y);
      a1.z = fmaf(v1.z, c1, a1.z); a1.w = fmaf(v1.w, c1, a1.w);
    }
    if (e < dp) {
      int sl = base8 + (e >> 1);
      int si0 = __shfl(mq.x, sl);
      float c0 = __int_as_float(__shfl(mq.y, sl));
      float4 v0 = sX4[si0 * 8 + l];
      a0.x = fmaf(v0.x, c0, a0.x); a0.y = fmaf(v0.y, c0, a0.y);
      a0.z = fmaf(v0.z, c0, a0.z); a0.w = fmaf(v0.w, c0, a0.w);
    }
    for (int e2 = PRE; e2 < d; ++e2) {         // rare overflow (deg > 16)
      int rl = srcext[(size_t)node * CAP + e2];
      float cf = cfext[(size_t)node * CAP + e2];
      float4 v0 = sX4[rl * 8 + l];
      a0.x = fmaf(v0.x, cf, a0.x); a0.y = fmaf(v0.y, cf, a0.y);
      a0.z = fmaf(v0.z, cf, a0.z); a0.w = fmaf(v0.w, cf, a0.w);
    }
    float4 o = make_float4(a0.x + a1.x, a0.y + a1.y, a0.z + a1.z, a0.w + a1.w);
    ((float4*)z)[(size_t)node * 32 + chunk * 8 + l] = o;
  }
}

// ---------------------------------------------------------------------------
// conv: h = relu(z @ W + b), in-place on zh; also score[row] = h . p
// tile: 64 rows x 128 cols, block 256 (8 rows x 4 cols per thread).
// W streams from L1/L2 with 1-stage software pipeline. Inner product uses
// float2 packed FMA (v_pk_fma_f32) — fp32 peak 157 TF needs packing; the
// scalar rate (m07: 103 TF) was round-10's 52%-VALUBusy wall.
// ---------------------------------------------------------------------------

__global__ __launch_bounds__(256) void conv_kernel(
    float* __restrict__ zh, const float* __restrict__ W,
    const float* __restrict__ bias, const float* __restrict__ p,
    float* __restrict__ score) {
  __shared__ float sZ[64 * HDIM];              // 32 KB
  int tid = threadIdx.x;
  size_t base = (size_t)blockIdx.x * 64 * HDIM;
  float4* sZ4 = (float4*)sZ;
  const float4* g4 = (const float4*)(zh + base);
  #pragma unroll
  for (int i = 0; i < 8; ++i) sZ4[i * 256 + tid] = g4[i * 256 + tid];
  __syncthreads();

  int col_t = tid & 31;
  int row_t = tid >> 5;
  int r0 = row_t * 8;
  const float4* W4 = (const float4*)W;

  v2f accA[8], accB[8];
  #pragma unroll
  for (int r = 0; r < 8; ++r) {
    accA[r] = (v2f)(0.f);
    accB[r] = (v2f)(0.f);
  }

  float4 w0 = W4[0 * 32 + col_t];
  float4 w1 = W4[1 * 32 + col_t];
  float4 w2 = W4[2 * 32 + col_t];
  float4 w3 = W4[3 * 32 + col_t];

  for (int k4 = 0; k4 < 32; ++k4) {
    int kn = k4 + 1;
    if (kn > 31) kn = 31;                      // branchless: redundant last load
    float4 nw0 = W4[(kn * 4 + 0) * 32 + col_t];
    float4 nw1 = W4[(kn * 4 + 1) * 32 + col_t];
    float4 nw2 = W4[(kn * 4 + 2) * 32 + col_t];
    float4 nw3 = W4[(kn * 4 + 3) * 32 + col_t];
    v2f w0a = {w0.x, w0.y}, w0b = {w0.z, w0.w};
    v2f w1a = {w1.x, w1.y}, w1b = {w1.z, w1.w};
    v2f w2a = {w2.x, w2.y}, w2b = {w2.z, w2.w};
    v2f w3a = {w3.x, w3.y}, w3b = {w3.z, w3.w};
    #pragma unroll
    for (int r = 0; r < 8; ++r) {
      float4 zr = sZ4[(r0 + r) * 32 + k4];
      v2f zx = {zr.x, zr.x};
      v2f zy = {zr.y, zr.y};
      v2f zz = {zr.z, zr.z};
      v2f zw = {zr.w, zr.w};
      accA[r] = pkfma(zx, w0a, accA[r]);
      accB[r] = pkfma(zx, w0b, accB[r]);
      accA[r] = pkfma(zy, w1a, accA[r]);
      accB[r] = pkfma(zy, w1b, accB[r]);
      accA[r] = pkfma(zz, w2a, accA[r]);
      accB[r] = pkfma(zz, w2b, accB[r]);
      accA[r] = pkfma(zw, w3a, accA[r]);
      accB[r] = pkfma(zw, w3b, accB[r]);
    }
    w0 = nw0; w1 = nw1; w2 = nw2; w3 = nw3;
  }

  float4 bv = ((const float4*)bias)[col_t];
  float4 pv = ((const float4*)p)[col_t];
  float4* out4 = (float4*)(zh + base);
  #pragma unroll
  for (int r = 0; r < 8; ++r) {
    float hx = fmaxf(accA[r].x + bv.x, 0.f);
    float hy = fmaxf(accA[r].y + bv.y, 0.f);
    float hz = fmaxf(accB[r].x + bv.z, 0.f);
    float hw = fmaxf(accB[r].y + bv.w, 0.f);
    float part = hx * pv.x + hy * pv.y + hz * pv.z + hw * pv.w;
    #pragma unroll
    for (int sft = 1; sft < 32; sft <<= 1) part += __shfl_xor(part, sft);
    out4[(r0 + r) * 32 + col_t] = make_float4(hx, hy, hz, hw);
    if (col_t == 0) score[blockIdx.x * 64 + r0 + r] = part;
  }
}

// ---------------------------------------------------------------------------
// per-graph top-K (K = P/2): P-thread bitonic sort, one element per thread.
// descending, tie-break lower index. Also zeroes cnt for next layer.
// ---------------------------------------------------------------------------

__global__ __launch_bounds__(1024) void topk_kernel(
    const float* __restrict__ score, const float* __restrict__ pnorm,
    int* __restrict__ sel, float* __restrict__ tanhv, int* __restrict__ newid,
    int* __restrict__ cnt_next, int P, int K) {
  __shared__ float sv[1024];
  __shared__ int si[1024];
  int g = blockIdx.x;
  int t = threadIdx.x;
  if (t < K) cnt_next[g * K + t] = 0;
  sv[t] = score[(size_t)g * P + t];
  si[t] = t;
  for (int size = 2; size <= P; size <<= 1) {
    for (int stride = size >> 1; stride; stride >>= 1) {
      __syncthreads();
      int j = t ^ stride;
      if (j > t) {
        float a = sv[t], b = sv[j];
        int ia = si[t], ib = si[j];
        bool tFirst = (a > b) || (a == b && ia < ib);
        bool up = ((t & size) == 0);
        if (up ? !tFirst : tFirst) {
          sv[t] = b; sv[j] = a;
          si[t] = ib; si[j] = ia;
        }
      }
    }
  }
  __syncthreads();
  if (t < K) {
    float v = sv[t];
    int oldg = g * P + si[t];
    int newg = g * K + t;
    sel[newg] = oldg;
    tanhv[newg] = tanhf(v / pnorm[0]);
    newid[oldg] = newg;
  }
}

// ---------------------------------------------------------------------------
// pool gather: xo[j] = h[sel[j]] * tanhv[j] for a 16-row chunk; float4 lanes.
// ---------------------------------------------------------------------------

__global__ __launch_bounds__(256) void pool_gather_kernel(
    const float* __restrict__ h, const int* __restrict__ sel,
    const float* __restrict__ tanhv, float* __restrict__ xo,
    float* __restrict__ pred, int K, int lc) {
  __shared__ int s_sel[16];
  __shared__ float s_th[16];
  __shared__ float4 smx[8][32], ssm[8][32];
  int b = blockIdx.x;
  int g = b >> lc;
  int chunk = b & ((1 << lc) - 1);
  int t = threadIdx.x;
  int j0 = chunk * 16;
  if (t < 16) {
    s_sel[t] = sel[g * K + j0 + t];
    s_th[t] = tanhv[g * K + j0 + t];
  }
  __syncthreads();
  int lane = t & 31, slot = t >> 5;
  const float4* h4 = (const float4*)h;
  float4* xo4 = (float4*)xo;
  float4 mx = make_float4(-INFINITY, -INFINITY, -INFINITY, -INFINITY);
  float4 sm = make_float4(0.f, 0.f, 0.f, 0.f);
  #pragma unroll
  for (int i = 0; i < 2; ++i) {
    int j = slot + i * 8;
    float th = s_th[j];
    float4 v = h4[(size_t)s_sel[j] * 32 + lane];
    v.x *= th; v.y *= th; v.z *= th; v.w *= th;
    xo4[(size_t)(g * K + j0 + j) * 32 + lane] = v;
    mx.x = fmaxf(mx.x, v.x); mx.y = fmaxf(mx.y, v.y);
    mx.z = fmaxf(mx.z, v.z); mx.w = fmaxf(mx.w, v.w);
    sm.x += v.x; sm.y += v.y; sm.z += v.z; sm.w += v.w;
  }
  smx[slot][lane] = mx;
  ssm[slot][lane] = sm;
  __syncthreads();
  if (slot == 0) {
    #pragma unroll
    for (int s2 = 1; s2 < 8; ++s2) {
      float4 m2 = smx[s2][lane], s3 = ssm[s2][lane];
      mx.x = fmaxf(mx.x, m2.x); mx.y = fmaxf(mx.y, m2.y);
      mx.z = fmaxf(mx.z, m2.z); mx.w = fmaxf(mx.w, m2.w);
      sm.x += s3.x; sm.y += s3.y; sm.z += s3.z; sm.w += s3.w;
    }
    float4* pred4 = (float4*)pred;
    pred4[(size_t)(g * 32 + chunk) * 64 + lane] = mx;
    pred4[(size_t)(g * 32 + chunk) * 64 + 32 + lane] = sm;
  }
}

// ---------------------------------------------------------------------------
// pool combine: reduce C chunk-partials per graph, accumulate into out
// ---------------------------------------------------------------------------

__global__ __launch_bounds__(64) void pool_combine_kernel(
    const float* __restrict__ pred, float* __restrict__ out, int K, int C) {
  int g = blockIdx.x;
  int t = threadIdx.x;
  const float4* pred4 = (const float4*)pred;
  float4* out4 = (float4*)out;
  if (t < 32) {
    float4 mx = make_float4(-INFINITY, -INFINITY, -INFINITY, -INFINITY);
    for (int c = 0; c < C; ++c) {
      float4 v = pred4[(size_t)(g * 32 + c) * 64 + t];
      mx.x = fmaxf(mx.x, v.x); mx.y = fmaxf(mx.y, v.y);
      mx.z = fmaxf(mx.z, v.z); mx.w = fmaxf(mx.w, v.w);
    }
    float4 o = out4[g * 64 + t];
    o.x += mx.x; o.y += mx.y; o.z += mx.z; o.w += mx.w;
    out4[g * 64 + t] = o;
  } else {
    int l = t - 32;
    float4 sm = make_float4(0.f, 0.f, 0.f, 0.f);
    for (int c = 0; c < C; ++c) {
      float4 v = pred4[(size_t)(g * 32 + c) * 64 + 32 + l];
      sm.x += v.x; sm.y += v.y; sm.z += v.z; sm.w += v.w;
    }
    float inv = 1.0f / (float)K;
    float4 o = out4[g * 64 + 32 + l];
    o.x += sm.x * inv; o.y += sm.y * inv; o.z += sm.z * inv; o.w += sm.w * inv;
    out4[g * 64 + 32 + l] = o;
  }
}

// ---------------------------------------------------------------------------
// fused relabel + count for next layer (cnt zeroed by topk)
// ---------------------------------------------------------------------------

__global__ __launch_bounds__(256) void relabel_count_kernel(
    const int* __restrict__ in_r, const int* __restrict__ in_c,
    int* __restrict__ out_r, int* __restrict__ out_c,
    const int* __restrict__ newid, int* __restrict__ cnt) {
  int e = blockIdx.x * 256 + threadIdx.x;
  int r = in_r[e];
  if (r < 0) {
    out_r[e] = -1;
    out_c[e] = -1;
    return;
  }
  int nr = newid[r];
  int nc = newid[in_c[e]];
  if (nr < 0 || nc < 0) {
    out_r[e] = -1;
    out_c[e] = -1;
  } else {
    out_r[e] = nr;
    out_c[e] = nc;
    atomicAdd(&cnt[nc], 1);
  }
}

// ---------------------------------------------------------------------------
// launch
// ---------------------------------------------------------------------------

extern "C" void kernel_launch(void* const* d_in, const int* in_sizes, int n_in,
                              void* d_out, int out_size, void* d_ws, size_t ws_size,
                              hipStream_t stream) {
  const float* x0 = (const float*)d_in[0];
  const int* erow = (const int*)d_in[1];
  const int* ecol = (const int*)d_in[2];
  const float* Wm[3] = {(const float*)d_in[3], (const float*)d_in[6], (const float*)d_in[9]};
  const float* bm[3] = {(const float*)d_in[4], (const float*)d_in[7], (const float*)d_in[10]};
  const float* pm[3] = {(const float*)d_in[5], (const float*)d_in[8], (const float*)d_in[11]};

  char* w = (char*)d_ws;
  size_t off = 0;
  auto alloc = [&](size_t bytes) -> void* {
    void* ptr = w + off;
    off = (off + bytes + 255) & ~(size_t)255;
    return ptr;
  };
  int* cur_row = (int*)alloc((size_t)NEDGE * 4);
  int* cur_col = (int*)alloc((size_t)NEDGE * 4);
  int2* meta16 = (int2*)alloc((size_t)NMAX * PRE * 8);
  int* srcext  = (int*)alloc((size_t)NMAX * CAP * 4);
  float* cfext = (float*)alloc((size_t)NMAX * CAP * 4);
  int* cnt     = (int*)alloc((size_t)NMAX * 4);
  int* cursor  = (int*)alloc((size_t)NMAX * 4);
  float* dinv  = (float*)alloc((size_t)NMAX * 4);
  int* newid   = (int*)alloc((size_t)NMAX * 4);
  float* score = (float*)alloc((size_t)NMAX * 4);
  int* sel     = (int*)alloc((size_t)BG * 512 * 4);
  float* tanhv = (float*)alloc((size_t)BG * 512 * 4);
  float* pn    = (float*)alloc(256);
  float* pred  = (float*)alloc((size_t)BG * 32 * 256 * 4);
  float* zh    = (float*)alloc((size_t)NMAX * HDIM * 4);
  float* x1    = (float*)alloc((size_t)BG * 512 * HDIM * 4);
  float* x2    = (float*)alloc((size_t)BG * 256 * HDIM * 4);
  float* x3    = (float*)alloc((size_t)BG * 128 * HDIM * 4);

  // allow >64 KB dynamic LDS for the agg kernel (L0 needs 132 KB)
  hipFuncSetAttribute((const void*)agg_lds_kernel,
                      hipFuncAttributeMaxDynamicSharedMemorySize, 152 * 1024);

  hipMemsetAsync(d_out, 0, (size_t)out_size * 4, stream);
  hipMemsetAsync(cnt, 0, (size_t)NMAX * 4, stream);
  pnorm_kernel<<<3, 128, 0, stream>>>(pm[0], pm[1], pm[2], pn);
  count_kernel<<<NEDGE / 256, 256, 0, stream>>>(ecol, cnt);

  const float* xin = x0;
  float* xout[3] = {x1, x2, x3};
  int Ps[3] = {1024, 512, 256};
  int LCs[3] = {5, 4, 3};     // log2(K/16)

  for (int L = 0; L < 3; ++L) {
    int P = Ps[L];
    int K = P >> 1;
    int n = BG * P;
    int lc = LCs[L];
    int C = 1 << lc;
    const int* in_r = (L == 0) ? erow : cur_row;
    const int* in_c = (L == 0) ? ecol : cur_col;
    size_t ldsBytes = (size_t)(P * 33) * 4;

    prep_kernel<<<n / 256, 256, 0, stream>>>(cnt, dinv, cursor, newid);
    fill_kernel<<<NEDGE / 256, 256, 0, stream>>>(in_r, in_c, dinv, cursor,
                                                 meta16, srcext, cfext, P - 1);
    agg_lds_kernel<<<BG * CHUNKS, 1024, ldsBytes, stream>>>(
        xin, zh, meta16, srcext, cfext, cursor, dinv, P);
    conv_kernel<<<n / 64, 256, 0, stream>>>(zh, Wm[L], bm[L], pm[L], score);
    topk_kernel<<<BG, P, 0, stream>>>(score, pn + L, sel, tanhv, newid, cnt, P, K);
    pool_gather_kernel<<<BG * C, 256, 0, stream>>>(zh, sel, tanhv, xout[L], pred, K, lc);
    pool_combine_kernel<<<BG, 64, 0, stream>>>(pred, (float*)d_out, K, C);
    if (L < 2) relabel_count_kernel<<<NEDGE / 256, 256, 0, stream>>>(
        in_r, in_c, cur_row, cur_col, newid, cnt);
    xin = xout[L];
  }
}

// Round 12
// 526.311 us; speedup vs baseline: 1.0265x; 1.0015x over previous
//
#include <hip/hip_runtime.h>
#include <math.h>

#define BG   128            // graphs
#define NPER 1024           // nodes per graph, level 0
#define HDIM 128            // hidden
#define NEDGE (BG * NPER * 8)
#define NMAX (BG * NPER)    // 131072
#define CAP  48             // per-node edge capacity (Poisson(8) tail ~1e-15)
#define PRE  16             // packed-meta entries per node (P(deg>16) ~ 0.4%)
#define CHUNKS 4            // 128 / 32 channels per agg chunk
#define CROWS 128           // conv tile rows (halves W L1-redundancy traffic)

typedef float v2f __attribute__((ext_vector_type(2)));

static __device__ __forceinline__ v2f pkfma(v2f a, v2f b, v2f c) {
#if __has_builtin(__builtin_elementwise_fma)
  return __builtin_elementwise_fma(a, b, c);
#else
  v2f r; r.x = fmaf(a.x, b.x, c.x); r.y = fmaf(a.y, b.y, c.y); return r;
#endif
}

// ---------------------------------------------------------------------------
// L0 in-degree count from the input edge list (cnt pre-zeroed) + zero cursor
// ---------------------------------------------------------------------------

__global__ __launch_bounds__(256) void count_kernel(
    const int* __restrict__ ec, int* __restrict__ cnt,
    int* __restrict__ cursor, int n0) {
  int e = blockIdx.x * 256 + threadIdx.x;
  if (e < n0) cursor[e] = 0;
  atomicAdd(&cnt[ec[e]], 1);
}

// ---------------------------------------------------------------------------
// fill: packed per-node meta (graph-LOCAL src, coef) for the first PRE edges;
// overflow (rare) to srcext/cfext. dinv computed on the fly from cnt.
// ---------------------------------------------------------------------------

__global__ __launch_bounds__(256) void fill_kernel(
    const int* __restrict__ cr, const int* __restrict__ cc,
    const int* __restrict__ cnt, int* __restrict__ cursor,
    int2* __restrict__ meta16, int* __restrict__ srcext,
    float* __restrict__ cfext, int mask) {
  int e = blockIdx.x * 256 + threadIdx.x;
  int c = cc[e];
  if (c >= 0) {
    int r = cr[e];
    int pos = atomicAdd(&cursor[c], 1);
    float cf = rsqrtf((float)cnt[r] + 1.0f) * rsqrtf((float)cnt[c] + 1.0f);
    int rl = r & mask;                  // graph-local row index
    if (pos < PRE) {
      meta16[(size_t)c * PRE + pos] = make_int2(rl, __float_as_int(cf));
    } else if (pos < CAP) {
      srcext[(size_t)c * CAP + pos] = rl;
      cfext[(size_t)c * CAP + pos] = cf;
    }
  }
}

// ---------------------------------------------------------------------------
// LDS-resident aggregation, barrier-free gather phase (round-11 design):
//  block = (graph, 32-channel chunk); stage x slice + dinv(cnt) -> LDS, one
//  barrier, then each 8-lane group walks its dsts independently (meta via
//  coalesced int4 + __shfl broadcast, rows via LDS ds_read_b128).
// ---------------------------------------------------------------------------

extern __shared__ float ldsbuf[];

__global__ __launch_bounds__(1024) void agg_lds_kernel(
    const float* __restrict__ x, float* __restrict__ z,
    const int2* __restrict__ meta16, const int* __restrict__ srcext,
    const float* __restrict__ cfext, const int* __restrict__ deg,
    int npg) {
  float* sX = ldsbuf;                          // [npg][32]
  float* sDinv = sX + npg * 32;                // [npg]
  int g = blockIdx.x >> 2;
  int chunk = blockIdx.x & 3;
  int t = threadIdx.x;
  int base = g * npg;

  const float4* x4 = (const float4*)x;
  float4* sX4 = (float4*)sX;
  for (int i = t; i < npg * 8; i += 1024) {
    int r = i >> 3, l8 = i & 7;
    sX4[i] = x4[(size_t)(base + r) * 32 + chunk * 8 + l8];
  }
  for (int i = t; i < npg; i += 1024)
    sDinv[i] = rsqrtf((float)deg[base + i] + 1.0f);
  __syncthreads();

  int dl = t >> 3, l = t & 7;                  // dst-local slot, lane 0..7
  int base8 = (t & 63) & 56;                   // 8-lane group base within wave
  const int4* m4 = (const int4*)meta16;
  for (int dst = dl; dst < npg; dst += 128) {
    int node = base + dst;
    int4 mq = m4[(size_t)node * 8 + l];        // edges 2l, 2l+1 (coalesced)
    int d = deg[node];
    if (d > CAP) d = CAP;
    float dc = sDinv[dst];
    float s0 = dc * dc;
    float4 row = sX4[dst * 8 + l];
    float4 a0 = make_float4(row.x * s0, row.y * s0, row.z * s0, row.w * s0);
    float4 a1 = make_float4(0.f, 0.f, 0.f, 0.f);
    int dp = d < PRE ? d : PRE;
    int e = 0;
    for (; e + 1 < dp; e += 2) {
      int sl = base8 + (e >> 1);
      int si0 = __shfl(mq.x, sl);
      int si1 = __shfl(mq.z, sl);
      float c0 = __int_as_float(__shfl(mq.y, sl));
      float c1 = __int_as_float(__shfl(mq.w, sl));
      float4 v0 = sX4[si0 * 8 + l];
      float4 v1 = sX4[si1 * 8 + l];
      a0.x = fmaf(v0.x, c0, a0.x); a0.y = fmaf(v0.y, c0, a0.y);
      a0.z = fmaf(v0.z, c0, a0.z); a0.w = fmaf(v0.w, c0, a0.w);
      a1.x = fmaf(v1.x, c1, a1.x); a1.y = fmaf(v1.y, c1, a1.y);
      a1.z = fmaf(v1.z, c1, a1.z); a1.w = fmaf(v1.w, c1, a1.w);
    }
    if (e < dp) {
      int sl = base8 + (e >> 1);
      int si0 = __shfl(mq.x, sl);
      float c0 = __int_as_float(__shfl(mq.y, sl));
      float4 v0 = sX4[si0 * 8 + l];
      a0.x = fmaf(v0.x, c0, a0.x); a0.y = fmaf(v0.y, c0, a0.y);
      a0.z = fmaf(v0.z, c0, a0.z); a0.w = fmaf(v0.w, c0, a0.w);
    }
    for (int e2 = PRE; e2 < d; ++e2) {         // rare overflow (deg > 16)
      int rl = srcext[(size_t)node * CAP + e2];
      float cf = cfext[(size_t)node * CAP + e2];
      float4 v0 = sX4[rl * 8 + l];
      a0.x = fmaf(v0.x, cf, a0.x); a0.y = fmaf(v0.y, cf, a0.y);
      a0.z = fmaf(v0.z, cf, a0.z); a0.w = fmaf(v0.w, cf, a0.w);
    }
    float4 o = make_float4(a0.x + a1.x, a0.y + a1.y, a0.z + a1.z, a0.w + a1.w);
    ((float4*)z)[(size_t)node * 32 + chunk * 8 + l] = o;
  }
}

// ---------------------------------------------------------------------------
// conv: h = relu(z @ W + b) in-place on zh; score = h . p; newid init = -1.
// tile: 128 rows x 128 cols, block 256 (16 rows x 4 cols per thread) —
// W L1-redundancy per FLOP halves vs 64-row tile (round-11 analysis: W L1
// traffic ~1 GB was the conv stall). LDS 64 KB -> 2 blocks/CU.
// ---------------------------------------------------------------------------

__global__ __launch_bounds__(256) void conv_kernel(
    float* __restrict__ zh, const float* __restrict__ W,
    const float* __restrict__ bias, const float* __restrict__ p,
    float* __restrict__ score, int* __restrict__ newid) {
  __shared__ float sZ[CROWS * HDIM];           // 64 KB
  int tid = threadIdx.x;
  size_t base = (size_t)blockIdx.x * CROWS * HDIM;
  float4* sZ4 = (float4*)sZ;
  const float4* g4 = (const float4*)(zh + base);
  #pragma unroll
  for (int i = 0; i < 16; ++i) sZ4[i * 256 + tid] = g4[i * 256 + tid];
  if (tid < CROWS) newid[blockIdx.x * CROWS + tid] = -1;
  __syncthreads();

  int col_t = tid & 31;
  int row_t = tid >> 5;
  int r0 = row_t * 16;
  const float4* W4 = (const float4*)W;

  v2f accA[16], accB[16];
  #pragma unroll
  for (int r = 0; r < 16; ++r) {
    accA[r] = (v2f)(0.f);
    accB[r] = (v2f)(0.f);
  }

  float4 w0 = W4[0 * 32 + col_t];
  float4 w1 = W4[1 * 32 + col_t];
  float4 w2 = W4[2 * 32 + col_t];
  float4 w3 = W4[3 * 32 + col_t];

  for (int k4 = 0; k4 < 32; ++k4) {
    int kn = k4 + 1;
    if (kn > 31) kn = 31;                      // branchless: redundant last load
    float4 nw0 = W4[(kn * 4 + 0) * 32 + col_t];
    float4 nw1 = W4[(kn * 4 + 1) * 32 + col_t];
    float4 nw2 = W4[(kn * 4 + 2) * 32 + col_t];
    float4 nw3 = W4[(kn * 4 + 3) * 32 + col_t];
    v2f w0a = {w0.x, w0.y}, w0b = {w0.z, w0.w};
    v2f w1a = {w1.x, w1.y}, w1b = {w1.z, w1.w};
    v2f w2a = {w2.x, w2.y}, w2b = {w2.z, w2.w};
    v2f w3a = {w3.x, w3.y}, w3b = {w3.z, w3.w};
    #pragma unroll
    for (int r = 0; r < 16; ++r) {
      float4 zr = sZ4[(r0 + r) * 32 + k4];
      v2f zx = {zr.x, zr.x};
      v2f zy = {zr.y, zr.y};
      v2f zz = {zr.z, zr.z};
      v2f zw = {zr.w, zr.w};
      accA[r] = pkfma(zx, w0a, accA[r]);
      accB[r] = pkfma(zx, w0b, accB[r]);
      accA[r] = pkfma(zy, w1a, accA[r]);
      accB[r] = pkfma(zy, w1b, accB[r]);
      accA[r] = pkfma(zz, w2a, accA[r]);
      accB[r] = pkfma(zz, w2b, accB[r]);
      accA[r] = pkfma(zw, w3a, accA[r]);
      accB[r] = pkfma(zw, w3b, accB[r]);
    }
    w0 = nw0; w1 = nw1; w2 = nw2; w3 = nw3;
  }

  float4 bv = ((const float4*)bias)[col_t];
  float4 pv = ((const float4*)p)[col_t];
  float4* out4 = (float4*)(zh + base);
  #pragma unroll
  for (int r = 0; r < 16; ++r) {
    float hx = fmaxf(accA[r].x + bv.x, 0.f);
    float hy = fmaxf(accA[r].y + bv.y, 0.f);
    float hz = fmaxf(accB[r].x + bv.z, 0.f);
    float hw = fmaxf(accB[r].y + bv.w, 0.f);
    float part = hx * pv.x + hy * pv.y + hz * pv.z + hw * pv.w;
    #pragma unroll
    for (int sft = 1; sft < 32; sft <<= 1) part += __shfl_xor(part, sft);
    out4[(r0 + r) * 32 + col_t] = make_float4(hx, hy, hz, hw);
    if (col_t == 0) score[blockIdx.x * CROWS + r0 + r] = part;
  }
}

// ---------------------------------------------------------------------------
// per-graph top-K (K = P/2): P-thread bitonic sort, one element per thread.
// descending, tie-break lower index. Inline ||p||; zeroes next layer's
// cnt AND cursor. newid was -1-initialized by conv.
// ---------------------------------------------------------------------------

__global__ __launch_bounds__(1024) void topk_kernel(
    const float* __restrict__ score, const float* __restrict__ p,
    int* __restrict__ sel, float* __restrict__ tanhv, int* __restrict__ newid,
    int* __restrict__ cnt_next, int* __restrict__ cursor_next, int P, int K) {
  __shared__ float sv[1024];
  __shared__ int si[1024];
  __shared__ float s_pn;
  int g = blockIdx.x;
  int t = threadIdx.x;
  // inline ||p|| (redundant per block, trivial cost)
  if (t < 128) { float v = p[t]; sv[t] = v * v; }
  __syncthreads();
  for (int off = 64; off; off >>= 1) {
    if (t < off) sv[t] += sv[t + off];
    __syncthreads();
  }
  if (t == 0) s_pn = sqrtf(sv[0]);
  __syncthreads();
  float pn = s_pn;
  if (t < K) {
    cnt_next[g * K + t] = 0;
    cursor_next[g * K + t] = 0;
  }
  sv[t] = score[(size_t)g * P + t];
  si[t] = t;
  for (int size = 2; size <= P; size <<= 1) {
    for (int stride = size >> 1; stride; stride >>= 1) {
      __syncthreads();
      int j = t ^ stride;
      if (j > t) {
        float a = sv[t], b = sv[j];
        int ia = si[t], ib = si[j];
        bool tFirst = (a > b) || (a == b && ia < ib);
        bool up = ((t & size) == 0);
        if (up ? !tFirst : tFirst) {
          sv[t] = b; sv[j] = a;
          si[t] = ib; si[j] = ia;
        }
      }
    }
  }
  __syncthreads();
  if (t < K) {
    float v = sv[t];
    int oldg = g * P + si[t];
    int newg = g * K + t;
    sel[newg] = oldg;
    tanhv[newg] = tanhf(v / pn);
    newid[oldg] = newg;
  }
}

// ---------------------------------------------------------------------------
// pool gather: xo[j] = h[sel[j]] * tanhv[j] for a 16-row chunk; float4 lanes.
// ---------------------------------------------------------------------------

__global__ __launch_bounds__(256) void pool_gather_kernel(
    const float* __restrict__ h, const int* __restrict__ sel,
    const float* __restrict__ tanhv, float* __restrict__ xo,
    float* __restrict__ pred, int K, int lc) {
  __shared__ int s_sel[16];
  __shared__ float s_th[16];
  __shared__ float4 smx[8][32], ssm[8][32];
  int b = blockIdx.x;
  int g = b >> lc;
  int chunk = b & ((1 << lc) - 1);
  int t = threadIdx.x;
  int j0 = chunk * 16;
  if (t < 16) {
    s_sel[t] = sel[g * K + j0 + t];
    s_th[t] = tanhv[g * K + j0 + t];
  }
  __syncthreads();
  int lane = t & 31, slot = t >> 5;
  const float4* h4 = (const float4*)h;
  float4* xo4 = (float4*)xo;
  float4 mx = make_float4(-INFINITY, -INFINITY, -INFINITY, -INFINITY);
  float4 sm = make_float4(0.f, 0.f, 0.f, 0.f);
  #pragma unroll
  for (int i = 0; i < 2; ++i) {
    int j = slot + i * 8;
    float th = s_th[j];
    float4 v = h4[(size_t)s_sel[j] * 32 + lane];
    v.x *= th; v.y *= th; v.z *= th; v.w *= th;
    xo4[(size_t)(g * K + j0 + j) * 32 + lane] = v;
    mx.x = fmaxf(mx.x, v.x); mx.y = fmaxf(mx.y, v.y);
    mx.z = fmaxf(mx.z, v.z); mx.w = fmaxf(mx.w, v.w);
    sm.x += v.x; sm.y += v.y; sm.z += v.z; sm.w += v.w;
  }
  smx[slot][lane] = mx;
  ssm[slot][lane] = sm;
  __syncthreads();
  if (slot == 0) {
    #pragma unroll
    for (int s2 = 1; s2 < 8; ++s2) {
      float4 m2 = smx[s2][lane], s3 = ssm[s2][lane];
      mx.x = fmaxf(mx.x, m2.x); mx.y = fmaxf(mx.y, m2.y);
      mx.z = fmaxf(mx.z, m2.z); mx.w = fmaxf(mx.w, m2.w);
      sm.x += s3.x; sm.y += s3.y; sm.z += s3.z; sm.w += s3.w;
    }
    float4* pred4 = (float4*)pred;
    pred4[(size_t)(g * 32 + chunk) * 64 + lane] = mx;
    pred4[(size_t)(g * 32 + chunk) * 64 + 32 + lane] = sm;
  }
}

// ---------------------------------------------------------------------------
// pool combine: reduce C chunk-partials per graph, accumulate into out
// ---------------------------------------------------------------------------

__global__ __launch_bounds__(64) void pool_combine_kernel(
    const float* __restrict__ pred, float* __restrict__ out, int K, int C) {
  int g = blockIdx.x;
  int t = threadIdx.x;
  const float4* pred4 = (const float4*)pred;
  float4* out4 = (float4*)out;
  if (t < 32) {
    float4 mx = make_float4(-INFINITY, -INFINITY, -INFINITY, -INFINITY);
    for (int c = 0; c < C; ++c) {
      float4 v = pred4[(size_t)(g * 32 + c) * 64 + t];
      mx.x = fmaxf(mx.x, v.x); mx.y = fmaxf(mx.y, v.y);
      mx.z = fmaxf(mx.z, v.z); mx.w = fmaxf(mx.w, v.w);
    }
    float4 o = out4[g * 64 + t];
    o.x += mx.x; o.y += mx.y; o.z += mx.z; o.w += mx.w;
    out4[g * 64 + t] = o;
  } else {
    int l = t - 32;
    float4 sm = make_float4(0.f, 0.f, 0.f, 0.f);
    for (int c = 0; c < C; ++c) {
      float4 v = pred4[(size_t)(g * 32 + c) * 64 + 32 + l];
      sm.x += v.x; sm.y += v.y; sm.z += v.z; sm.w += v.w;
    }
    float inv = 1.0f / (float)K;
    float4 o = out4[g * 64 + 32 + l];
    o.x += sm.x * inv; o.y += sm.y * inv; o.z += sm.z * inv; o.w += sm.w * inv;
    out4[g * 64 + 32 + l] = o;
  }
}

// ---------------------------------------------------------------------------
// fused relabel + count for next layer (cnt zeroed by topk)
// ---------------------------------------------------------------------------

__global__ __launch_bounds__(256) void relabel_count_kernel(
    const int* __restrict__ in_r, const int* __restrict__ in_c,
    int* __restrict__ out_r, int* __restrict__ out_c,
    const int* __restrict__ newid, int* __restrict__ cnt) {
  int e = blockIdx.x * 256 + threadIdx.x;
  int r = in_r[e];
  if (r < 0) {
    out_r[e] = -1;
    out_c[e] = -1;
    return;
  }
  int nr = newid[r];
  int nc = newid[in_c[e]];
  if (nr < 0 || nc < 0) {
    out_r[e] = -1;
    out_c[e] = -1;
  } else {
    out_r[e] = nr;
    out_c[e] = nc;
    atomicAdd(&cnt[nc], 1);
  }
}

// ---------------------------------------------------------------------------
// launch
// ---------------------------------------------------------------------------

extern "C" void kernel_launch(void* const* d_in, const int* in_sizes, int n_in,
                              void* d_out, int out_size, void* d_ws, size_t ws_size,
                              hipStream_t stream) {
  const float* x0 = (const float*)d_in[0];
  const int* erow = (const int*)d_in[1];
  const int* ecol = (const int*)d_in[2];
  const float* Wm[3] = {(const float*)d_in[3], (const float*)d_in[6], (const float*)d_in[9]};
  const float* bm[3] = {(const float*)d_in[4], (const float*)d_in[7], (const float*)d_in[10]};
  const float* pm[3] = {(const float*)d_in[5], (const float*)d_in[8], (const float*)d_in[11]};

  char* w = (char*)d_ws;
  size_t off = 0;
  auto alloc = [&](size_t bytes) -> void* {
    void* ptr = w + off;
    off = (off + bytes + 255) & ~(size_t)255;
    return ptr;
  };
  int* cur_row = (int*)alloc((size_t)NEDGE * 4);
  int* cur_col = (int*)alloc((size_t)NEDGE * 4);
  int2* meta16 = (int2*)alloc((size_t)NMAX * PRE * 8);
  int* srcext  = (int*)alloc((size_t)NMAX * CAP * 4);
  float* cfext = (float*)alloc((size_t)NMAX * CAP * 4);
  int* cnt     = (int*)alloc((size_t)NMAX * 4);
  int* cursor  = (int*)alloc((size_t)NMAX * 4);
  int* newid   = (int*)alloc((size_t)NMAX * 4);
  float* score = (float*)alloc((size_t)NMAX * 4);
  int* sel     = (int*)alloc((size_t)BG * 512 * 4);
  float* tanhv = (float*)alloc((size_t)BG * 512 * 4);
  float* pred  = (float*)alloc((size_t)BG * 32 * 256 * 4);
  float* zh    = (float*)alloc((size_t)NMAX * HDIM * 4);
  float* x1    = (float*)alloc((size_t)BG * 512 * HDIM * 4);
  float* x2    = (float*)alloc((size_t)BG * 256 * HDIM * 4);
  float* x3    = (float*)alloc((size_t)BG * 128 * HDIM * 4);

  // allow >64 KB dynamic LDS for the agg kernel (L0 needs 132 KB)
  hipFuncSetAttribute((const void*)agg_lds_kernel,
                      hipFuncAttributeMaxDynamicSharedMemorySize, 152 * 1024);

  hipMemsetAsync(d_out, 0, (size_t)out_size * 4, stream);
  hipMemsetAsync(cnt, 0, (size_t)NMAX * 4, stream);
  count_kernel<<<NEDGE / 256, 256, 0, stream>>>(ecol, cnt, cursor, NMAX);

  const float* xin = x0;
  float* xout[3] = {x1, x2, x3};
  int Ps[3] = {1024, 512, 256};
  int LCs[3] = {5, 4, 3};     // log2(K/16)

  for (int L = 0; L < 3; ++L) {
    int P = Ps[L];
    int K = P >> 1;
    int n = BG * P;
    int lc = LCs[L];
    int C = 1 << lc;
    const int* in_r = (L == 0) ? erow : cur_row;
    const int* in_c = (L == 0) ? ecol : cur_col;
    size_t ldsBytes = (size_t)(P * 33) * 4;

    fill_kernel<<<NEDGE / 256, 256, 0, stream>>>(in_r, in_c, cnt, cursor,
                                                 meta16, srcext, cfext, P - 1);
    agg_lds_kernel<<<BG * CHUNKS, 1024, ldsBytes, stream>>>(
        xin, zh, meta16, srcext, cfext, cnt, P);
    conv_kernel<<<n / CROWS, 256, 0, stream>>>(zh, Wm[L], bm[L], pm[L], score, newid);
    topk_kernel<<<BG, P, 0, stream>>>(score, pm[L], sel, tanhv, newid,
                                      cnt, cursor, P, K);
    pool_gather_kernel<<<BG * C, 256, 0, stream>>>(zh, sel, tanhv, xout[L], pred, K, lc);
    pool_combine_kernel<<<BG, 64, 0, stream>>>(pred, (float*)d_out, K, C);
    if (L < 2) relabel_count_kernel<<<NEDGE / 256, 256, 0, stream>>>(
        in_r, in_c, cur_row, cur_col, newid, cnt);
    xin = xout[L];
  }
}

// Round 13
// 496.290 us; speedup vs baseline: 1.0886x; 1.0605x over previous
//
#include <hip/hip_runtime.h>
#include <math.h>

#define BG   128            // graphs
#define NPER 1024           // nodes per graph, level 0
#define HDIM 128            // hidden
#define NEDGE (BG * NPER * 8)
#define NMAX (BG * NPER)    // 131072
#define CAP  48             // per-node edge capacity (Poisson(8) tail ~1e-15)
#define PRE  16             // packed-meta entries per node (P(deg>16) ~ 0.4%)
#define CHUNKS 4            // 128 / 32 channels per agg chunk
#define CROWS 64            // conv tile rows (round-12: 128 rows regressed, occupancy)

typedef float v2f __attribute__((ext_vector_type(2)));

static __device__ __forceinline__ v2f pkfma(v2f a, v2f b, v2f c) {
#if __has_builtin(__builtin_elementwise_fma)
  return __builtin_elementwise_fma(a, b, c);
#else
  v2f r; r.x = fmaf(a.x, b.x, c.x); r.y = fmaf(a.y, b.y, c.y); return r;
#endif
}

// ordered-uint encoding: monotone float->uint bijection; 0 is below -inf
static __device__ __forceinline__ unsigned enc_f(float f) {
  unsigned b = __float_as_uint(f);
  return (b & 0x80000000u) ? ~b : (b | 0x80000000u);
}
static __device__ __forceinline__ float dec_f(unsigned u) {
  unsigned b = (u & 0x80000000u) ? (u & 0x7FFFFFFFu) : ~u;
  return __uint_as_float(b);
}

// ---------------------------------------------------------------------------
// L0 in-degree count from the input edge list (cnt pre-zeroed) + zero cursor
// ---------------------------------------------------------------------------

__global__ __launch_bounds__(256) void count_kernel(
    const int* __restrict__ ec, int* __restrict__ cnt,
    int* __restrict__ cursor, int n0) {
  int e = blockIdx.x * 256 + threadIdx.x;
  if (e < n0) cursor[e] = 0;
  atomicAdd(&cnt[ec[e]], 1);
}

// ---------------------------------------------------------------------------
// fill: packed per-node meta (graph-LOCAL src, coef) for the first PRE edges;
// overflow (rare) to srcext/cfext. dinv computed on the fly from cnt.
// ---------------------------------------------------------------------------

__global__ __launch_bounds__(256) void fill_kernel(
    const int* __restrict__ cr, const int* __restrict__ cc,
    const int* __restrict__ cnt, int* __restrict__ cursor,
    int2* __restrict__ meta16, int* __restrict__ srcext,
    float* __restrict__ cfext, int mask) {
  int e = blockIdx.x * 256 + threadIdx.x;
  int c = cc[e];
  if (c >= 0) {
    int r = cr[e];
    int pos = atomicAdd(&cursor[c], 1);
    float cf = rsqrtf((float)cnt[r] + 1.0f) * rsqrtf((float)cnt[c] + 1.0f);
    int rl = r & mask;                  // graph-local row index
    if (pos < PRE) {
      meta16[(size_t)c * PRE + pos] = make_int2(rl, __float_as_int(cf));
    } else if (pos < CAP) {
      srcext[(size_t)c * CAP + pos] = rl;
      cfext[(size_t)c * CAP + pos] = cf;
    }
  }
}

// ---------------------------------------------------------------------------
// LDS-resident aggregation, barrier-free gather phase (round-11 design):
//  block = (graph, 32-channel chunk); stage x slice + dinv(cnt) -> LDS, one
//  barrier, then each 8-lane group walks its dsts independently (meta via
//  coalesced int4 + __shfl broadcast, rows via LDS ds_read_b128).
// ---------------------------------------------------------------------------

extern __shared__ float ldsbuf[];

__global__ __launch_bounds__(1024) void agg_lds_kernel(
    const float* __restrict__ x, float* __restrict__ z,
    const int2* __restrict__ meta16, const int* __restrict__ srcext,
    const float* __restrict__ cfext, const int* __restrict__ deg,
    int npg) {
  float* sX = ldsbuf;                          // [npg][32]
  float* sDinv = sX + npg * 32;                // [npg]
  int g = blockIdx.x >> 2;
  int chunk = blockIdx.x & 3;
  int t = threadIdx.x;
  int base = g * npg;

  const float4* x4 = (const float4*)x;
  float4* sX4 = (float4*)sX;
  for (int i = t; i < npg * 8; i += 1024) {
    int r = i >> 3, l8 = i & 7;
    sX4[i] = x4[(size_t)(base + r) * 32 + chunk * 8 + l8];
  }
  for (int i = t; i < npg; i += 1024)
    sDinv[i] = rsqrtf((float)deg[base + i] + 1.0f);
  __syncthreads();

  int dl = t >> 3, l = t & 7;                  // dst-local slot, lane 0..7
  int base8 = (t & 63) & 56;                   // 8-lane group base within wave
  const int4* m4 = (const int4*)meta16;
  for (int dst = dl; dst < npg; dst += 128) {
    int node = base + dst;
    int4 mq = m4[(size_t)node * 8 + l];        // edges 2l, 2l+1 (coalesced)
    int d = deg[node];
    if (d > CAP) d = CAP;
    float dc = sDinv[dst];
    float s0 = dc * dc;
    float4 row = sX4[dst * 8 + l];
    float4 a0 = make_float4(row.x * s0, row.y * s0, row.z * s0, row.w * s0);
    float4 a1 = make_float4(0.f, 0.f, 0.f, 0.f);
    int dp = d < PRE ? d : PRE;
    int e = 0;
    for (; e + 1 < dp; e += 2) {
      int sl = base8 + (e >> 1);
      int si0 = __shfl(mq.x, sl);
      int si1 = __shfl(mq.z, sl);
      float c0 = __int_as_float(__shfl(mq.y, sl));
      float c1 = __int_as_float(__shfl(mq.w, sl));
      float4 v0 = sX4[si0 * 8 + l];
      float4 v1 = sX4[si1 * 8 + l];
      a0.x = fmaf(v0.x, c0, a0.x); a0.y = fmaf(v0.y, c0, a0.y);
      a0.z = fmaf(v0.z, c0, a0.z); a0.w = fmaf(v0.w, c0, a0.w);
      a1.x = fmaf(v1.x, c1, a1.x); a1.y = fmaf(v1.y, c1, a1.y);
      a1.z = fmaf(v1.z, c1, a1.z); a1.w = fmaf(v1.w, c1, a1.w);
    }
    if (e < dp) {
      int sl = base8 + (e >> 1);
      int si0 = __shfl(mq.x, sl);
      float c0 = __int_as_float(__shfl(mq.y, sl));
      float4 v0 = sX4[si0 * 8 + l];
      a0.x = fmaf(v0.x, c0, a0.x); a0.y = fmaf(v0.y, c0, a0.y);
      a0.z = fmaf(v0.z, c0, a0.z); a0.w = fmaf(v0.w, c0, a0.w);
    }
    for (int e2 = PRE; e2 < d; ++e2) {         // rare overflow (deg > 16)
      int rl = srcext[(size_t)node * CAP + e2];
      float cf = cfext[(size_t)node * CAP + e2];
      float4 v0 = sX4[rl * 8 + l];
      a0.x = fmaf(v0.x, cf, a0.x); a0.y = fmaf(v0.y, cf, a0.y);
      a0.z = fmaf(v0.z, cf, a0.z); a0.w = fmaf(v0.w, cf, a0.w);
    }
    float4 o = make_float4(a0.x + a1.x, a0.y + a1.y, a0.z + a1.z, a0.w + a1.w);
    ((float4*)z)[(size_t)node * 32 + chunk * 8 + l] = o;
  }
}

// ---------------------------------------------------------------------------
// conv: h = relu(z @ W + b) in-place on zh; score = h . p; newid init = -1.
// tile: 64 rows x 128 cols, block 256 (8 rows x 4 cols/thread) — round-11's
// optimum (round-9 W-in-LDS and round-12 128-row tile both regressed on
// occupancy). W streams L1 w/ 1-stage pipeline; packed v_pk_fma_f32.
// ---------------------------------------------------------------------------

__global__ __launch_bounds__(256) void conv_kernel(
    float* __restrict__ zh, const float* __restrict__ W,
    const float* __restrict__ bias, const float* __restrict__ p,
    float* __restrict__ score, int* __restrict__ newid) {
  __shared__ float sZ[CROWS * HDIM];           // 32 KB
  int tid = threadIdx.x;
  size_t base = (size_t)blockIdx.x * CROWS * HDIM;
  float4* sZ4 = (float4*)sZ;
  const float4* g4 = (const float4*)(zh + base);
  #pragma unroll
  for (int i = 0; i < 8; ++i) sZ4[i * 256 + tid] = g4[i * 256 + tid];
  if (tid < CROWS) newid[blockIdx.x * CROWS + tid] = -1;
  __syncthreads();

  int col_t = tid & 31;
  int row_t = tid >> 5;
  int r0 = row_t * 8;
  const float4* W4 = (const float4*)W;

  v2f accA[8], accB[8];
  #pragma unroll
  for (int r = 0; r < 8; ++r) {
    accA[r] = (v2f)(0.f);
    accB[r] = (v2f)(0.f);
  }

  float4 w0 = W4[0 * 32 + col_t];
  float4 w1 = W4[1 * 32 + col_t];
  float4 w2 = W4[2 * 32 + col_t];
  float4 w3 = W4[3 * 32 + col_t];

  for (int k4 = 0; k4 < 32; ++k4) {
    int kn = k4 + 1;
    if (kn > 31) kn = 31;                      // branchless: redundant last load
    float4 nw0 = W4[(kn * 4 + 0) * 32 + col_t];
    float4 nw1 = W4[(kn * 4 + 1) * 32 + col_t];
    float4 nw2 = W4[(kn * 4 + 2) * 32 + col_t];
    float4 nw3 = W4[(kn * 4 + 3) * 32 + col_t];
    v2f w0a = {w0.x, w0.y}, w0b = {w0.z, w0.w};
    v2f w1a = {w1.x, w1.y}, w1b = {w1.z, w1.w};
    v2f w2a = {w2.x, w2.y}, w2b = {w2.z, w2.w};
    v2f w3a = {w3.x, w3.y}, w3b = {w3.z, w3.w};
    #pragma unroll
    for (int r = 0; r < 8; ++r) {
      float4 zr = sZ4[(r0 + r) * 32 + k4];
      v2f zx = {zr.x, zr.x};
      v2f zy = {zr.y, zr.y};
      v2f zz = {zr.z, zr.z};
      v2f zw = {zr.w, zr.w};
      accA[r] = pkfma(zx, w0a, accA[r]);
      accB[r] = pkfma(zx, w0b, accB[r]);
      accA[r] = pkfma(zy, w1a, accA[r]);
      accB[r] = pkfma(zy, w1b, accB[r]);
      accA[r] = pkfma(zz, w2a, accA[r]);
      accB[r] = pkfma(zz, w2b, accB[r]);
      accA[r] = pkfma(zw, w3a, accA[r]);
      accB[r] = pkfma(zw, w3b, accB[r]);
    }
    w0 = nw0; w1 = nw1; w2 = nw2; w3 = nw3;
  }

  float4 bv = ((const float4*)bias)[col_t];
  float4 pv = ((const float4*)p)[col_t];
  float4* out4 = (float4*)(zh + base);
  #pragma unroll
  for (int r = 0; r < 8; ++r) {
    float hx = fmaxf(accA[r].x + bv.x, 0.f);
    float hy = fmaxf(accA[r].y + bv.y, 0.f);
    float hz = fmaxf(accB[r].x + bv.z, 0.f);
    float hw = fmaxf(accB[r].y + bv.w, 0.f);
    float part = hx * pv.x + hy * pv.y + hz * pv.z + hw * pv.w;
    #pragma unroll
    for (int sft = 1; sft < 32; sft <<= 1) part += __shfl_xor(part, sft);
    out4[(r0 + r) * 32 + col_t] = make_float4(hx, hy, hz, hw);
    if (col_t == 0) score[blockIdx.x * CROWS + r0 + r] = part;
  }
}

// ---------------------------------------------------------------------------
// per-graph top-K (K = P/2): P-thread bitonic sort, one element per thread.
// descending, tie-break lower index. Inline ||p||; zeroes next layer's
// cnt AND cursor. newid was -1-initialized by conv.
// ---------------------------------------------------------------------------

__global__ __launch_bounds__(1024) void topk_kernel(
    const float* __restrict__ score, const float* __restrict__ p,
    int* __restrict__ sel, float* __restrict__ tanhv, int* __restrict__ newid,
    int* __restrict__ cnt_next, int* __restrict__ cursor_next, int P, int K) {
  __shared__ float sv[1024];
  __shared__ int si[1024];
  __shared__ float s_pn;
  int g = blockIdx.x;
  int t = threadIdx.x;
  if (t < 128) { float v = p[t]; sv[t] = v * v; }
  __syncthreads();
  for (int off = 64; off; off >>= 1) {
    if (t < off) sv[t] += sv[t + off];
    __syncthreads();
  }
  if (t == 0) s_pn = sqrtf(sv[0]);
  __syncthreads();
  float pn = s_pn;
  if (t < K) {
    cnt_next[g * K + t] = 0;
    cursor_next[g * K + t] = 0;
  }
  sv[t] = score[(size_t)g * P + t];
  si[t] = t;
  for (int size = 2; size <= P; size <<= 1) {
    for (int stride = size >> 1; stride; stride >>= 1) {
      __syncthreads();
      int j = t ^ stride;
      if (j > t) {
        float a = sv[t], b = sv[j];
        int ia = si[t], ib = si[j];
        bool tFirst = (a > b) || (a == b && ia < ib);
        bool up = ((t & size) == 0);
        if (up ? !tFirst : tFirst) {
          sv[t] = b; sv[j] = a;
          si[t] = ib; si[j] = ia;
        }
      }
    }
  }
  __syncthreads();
  if (t < K) {
    float v = sv[t];
    int oldg = g * P + si[t];
    int newg = g * K + t;
    sel[newg] = oldg;
    tanhv[newg] = tanhf(v / pn);
    newid[oldg] = newg;
  }
}

// ---------------------------------------------------------------------------
// merged post-topk stage (grid split):
//  blocks [0, BG*C): pool gather — xo = h[sel]*tanh, per-chunk max/sum folded
//    into per-layer accumulator acc via atomicMax(ordered-uint) / atomicAdd.
//  blocks [BG*C, ...): relabel + count for the next layer.
// ---------------------------------------------------------------------------

__global__ __launch_bounds__(256) void pool_relabel_kernel(
    const float* __restrict__ h, const int* __restrict__ sel,
    const float* __restrict__ tanhv, float* __restrict__ xo,
    unsigned* __restrict__ acc, int K, int lc, int ngather,
    const int* __restrict__ in_r, const int* __restrict__ in_c,
    int* __restrict__ out_r, int* __restrict__ out_c,
    const int* __restrict__ newid, int* __restrict__ cnt) {
  int b = blockIdx.x;
  int t = threadIdx.x;
  if (b >= ngather) {                          // ---- relabel part ----
    int e = (b - ngather) * 256 + t;
    int r = in_r[e];
    if (r < 0) {
      out_r[e] = -1;
      out_c[e] = -1;
      return;
    }
    int nr = newid[r];
    int nc = newid[in_c[e]];
    if (nr < 0 || nc < 0) {
      out_r[e] = -1;
      out_c[e] = -1;
    } else {
      out_r[e] = nr;
      out_c[e] = nc;
      atomicAdd(&cnt[nc], 1);
    }
    return;
  }
  // ---- gather part ----
  __shared__ int s_sel[16];
  __shared__ float s_th[16];
  __shared__ float4 smx[8][32], ssm[8][32];
  int g = b >> lc;
  int chunk = b & ((1 << lc) - 1);
  int j0 = chunk * 16;
  if (t < 16) {
    s_sel[t] = sel[g * K + j0 + t];
    s_th[t] = tanhv[g * K + j0 + t];
  }
  __syncthreads();
  int lane = t & 31, slot = t >> 5;
  const float4* h4 = (const float4*)h;
  float4* xo4 = (float4*)xo;
  float4 mx = make_float4(-INFINITY, -INFINITY, -INFINITY, -INFINITY);
  float4 sm = make_float4(0.f, 0.f, 0.f, 0.f);
  #pragma unroll
  for (int i = 0; i < 2; ++i) {
    int j = slot + i * 8;
    float th = s_th[j];
    float4 v = h4[(size_t)s_sel[j] * 32 + lane];
    v.x *= th; v.y *= th; v.z *= th; v.w *= th;
    xo4[(size_t)(g * K + j0 + j) * 32 + lane] = v;
    mx.x = fmaxf(mx.x, v.x); mx.y = fmaxf(mx.y, v.y);
    mx.z = fmaxf(mx.z, v.z); mx.w = fmaxf(mx.w, v.w);
    sm.x += v.x; sm.y += v.y; sm.z += v.z; sm.w += v.w;
  }
  smx[slot][lane] = mx;
  ssm[slot][lane] = sm;
  __syncthreads();
  if (slot == 0) {
    #pragma unroll
    for (int s2 = 1; s2 < 8; ++s2) {
      float4 m2 = smx[s2][lane], s3 = ssm[s2][lane];
      mx.x = fmaxf(mx.x, m2.x); mx.y = fmaxf(mx.y, m2.y);
      mx.z = fmaxf(mx.z, m2.z); mx.w = fmaxf(mx.w, m2.w);
      sm.x += s3.x; sm.y += s3.y; sm.z += s3.z; sm.w += s3.w;
    }
    unsigned* amax = acc + (size_t)g * 256;
    float* asum = (float*)(acc + (size_t)g * 256 + 128);
    int c0 = lane * 4;
    atomicMax(&amax[c0 + 0], enc_f(mx.x));
    atomicMax(&amax[c0 + 1], enc_f(mx.y));
    atomicMax(&amax[c0 + 2], enc_f(mx.z));
    atomicMax(&amax[c0 + 3], enc_f(mx.w));
    atomicAdd(&asum[c0 + 0], sm.x);
    atomicAdd(&asum[c0 + 1], sm.y);
    atomicAdd(&asum[c0 + 2], sm.z);
    atomicAdd(&asum[c0 + 3], sm.w);
  }
}

// ---------------------------------------------------------------------------
// final: out[g] = sum over layers of [decode(max), sum/K_L]
// ---------------------------------------------------------------------------

__global__ __launch_bounds__(256) void final_kernel(
    const unsigned* __restrict__ acc, float* __restrict__ out) {
  int g = blockIdx.x;
  int t = threadIdx.x;
  const float kinv[3] = {1.f / 512.f, 1.f / 256.f, 1.f / 128.f};
  float v = 0.f;
  if (t < 128) {
    #pragma unroll
    for (int L = 0; L < 3; ++L)
      v += dec_f(acc[(size_t)L * BG * 256 + g * 256 + t]);
  } else {
    #pragma unroll
    for (int L = 0; L < 3; ++L)
      v += __uint_as_float(acc[(size_t)L * BG * 256 + g * 256 + t]) * kinv[L];
  }
  out[g * 256 + t] = v;
}

// ---------------------------------------------------------------------------
// launch
// ---------------------------------------------------------------------------

extern "C" void kernel_launch(void* const* d_in, const int* in_sizes, int n_in,
                              void* d_out, int out_size, void* d_ws, size_t ws_size,
                              hipStream_t stream) {
  const float* x0 = (const float*)d_in[0];
  const int* erow = (const int*)d_in[1];
  const int* ecol = (const int*)d_in[2];
  const float* Wm[3] = {(const float*)d_in[3], (const float*)d_in[6], (const float*)d_in[9]};
  const float* bm[3] = {(const float*)d_in[4], (const float*)d_in[7], (const float*)d_in[10]};
  const float* pm[3] = {(const float*)d_in[5], (const float*)d_in[8], (const float*)d_in[11]};

  char* w = (char*)d_ws;
  size_t off = 0;
  auto alloc = [&](size_t bytes) -> void* {
    void* ptr = w + off;
    off = (off + bytes + 255) & ~(size_t)255;
    return ptr;
  };
  int* cur_row = (int*)alloc((size_t)NEDGE * 4);
  int* cur_col = (int*)alloc((size_t)NEDGE * 4);
  int2* meta16 = (int2*)alloc((size_t)NMAX * PRE * 8);
  int* srcext  = (int*)alloc((size_t)NMAX * CAP * 4);
  float* cfext = (float*)alloc((size_t)NMAX * CAP * 4);
  int* cnt     = (int*)alloc((size_t)NMAX * 4);
  int* cursor  = (int*)alloc((size_t)NMAX * 4);
  int* newid   = (int*)alloc((size_t)NMAX * 4);
  float* score = (float*)alloc((size_t)NMAX * 4);
  int* sel     = (int*)alloc((size_t)BG * 512 * 4);
  float* tanhv = (float*)alloc((size_t)BG * 512 * 4);
  unsigned* acc = (unsigned*)alloc((size_t)3 * BG * 256 * 4);
  float* zh    = (float*)alloc((size_t)NMAX * HDIM * 4);
  float* x1    = (float*)alloc((size_t)BG * 512 * HDIM * 4);
  float* x2    = (float*)alloc((size_t)BG * 256 * HDIM * 4);
  float* x3    = (float*)alloc((size_t)BG * 128 * HDIM * 4);

  // allow >64 KB dynamic LDS for the agg kernel (L0 needs 132 KB)
  hipFuncSetAttribute((const void*)agg_lds_kernel,
                      hipFuncAttributeMaxDynamicSharedMemorySize, 152 * 1024);

  hipMemsetAsync(cnt, 0, (size_t)NMAX * 4, stream);
  hipMemsetAsync(acc, 0, (size_t)3 * BG * 256 * 4, stream);  // 0 = below -inf
  count_kernel<<<NEDGE / 256, 256, 0, stream>>>(ecol, cnt, cursor, NMAX);

  const float* xin = x0;
  float* xout[3] = {x1, x2, x3};
  int Ps[3] = {1024, 512, 256};
  int LCs[3] = {5, 4, 3};     // log2(K/16)

  for (int L = 0; L < 3; ++L) {
    int P = Ps[L];
    int K = P >> 1;
    int n = BG * P;
    int lc = LCs[L];
    int C = 1 << lc;
    const int* in_r = (L == 0) ? erow : cur_row;
    const int* in_c = (L == 0) ? ecol : cur_col;
    size_t ldsBytes = (size_t)(P * 33) * 4;
    int ngather = BG * C;
    int nrelabel = (L < 2) ? NEDGE / 256 : 0;

    fill_kernel<<<NEDGE / 256, 256, 0, stream>>>(in_r, in_c, cnt, cursor,
                                                 meta16, srcext, cfext, P - 1);
    agg_lds_kernel<<<BG * CHUNKS, 1024, ldsBytes, stream>>>(
        xin, zh, meta16, srcext, cfext, cnt, P);
    conv_kernel<<<n / CROWS, 256, 0, stream>>>(zh, Wm[L], bm[L], pm[L], score, newid);
    topk_kernel<<<BG, P, 0, stream>>>(score, pm[L], sel, tanhv, newid,
                                      cnt, cursor, P, K);
    pool_relabel_kernel<<<ngather + nrelabel, 256, 0, stream>>>(
        zh, sel, tanhv, xout[L], acc + (size_t)L * BG * 256, K, lc, ngather,
        in_r, in_c, cur_row, cur_col, newid, cnt);
    xin = xout[L];
  }
  final_kernel<<<BG, 256, 0, stream>>>(acc, (float*)d_out);
}